// Round 12
// baseline (2046.802 us; speedup 1.0000x reference)
//
#include <hip/hip_runtime.h>
#include <hip/hip_bf16.h>
#include <stdint.h>
#include <math.h>

#define NIN_  512
#define NOUT_ 128
#define CIN_  128
#define COUT_ 32
#define MO_   4096   // NOUT*COUT
#define NBT_  32     // build batch (all of B)
#define RB_   16     // routed b-half width
#define NQ2_  32     // route n-chunks per half (16 n each; 4 n per wave)

typedef __attribute__((ext_vector_type(4))) float f32x4;

// ---------------------------------------------------------------------------
// K1 (fp32): u[n][bl(32)][mo] = sum_c W1[n][mo][c] * x[bl][n][c]
// grid = 8192 = 512 n * 16 mo-tiles(256); block 256 = 4 waves.
// (R10-verbatim — near BW-bound; R9 showed any fusion into it regresses)
// ---------------------------------------------------------------------------
__global__ __launch_bounds__(256) void k_build(const float* __restrict__ x,
                                               const float* __restrict__ W1,
                                               float* __restrict__ u) {
    const int n   = blockIdx.x >> 4;
    const int mt  = blockIdx.x & 15;
    const int mo0 = mt * 256;
    const int t   = threadIdx.x;
    const int l   = t & 63;
    const int bg  = t >> 6;

    __shared__ f32x4 xs4[32 * 32];   // [bl][cu]  16 KB
    __shared__ f32x4 ws4[256 * 8];   // swizzled   32 KB

    for (int k = t; k < NBT_ * 32; k += 256) {
        const int bl = k >> 5;
        const int cu = k & 31;
        xs4[k] = *(const f32x4*)(x + (((size_t)bl * NIN_ + n) * CIN_ + cu * 4));
    }

    const int cu8 = t & 7;
    const int row = t >> 3;

    float acc[4][8];
#pragma unroll
    for (int i = 0; i < 4; ++i)
#pragma unroll
        for (int j = 0; j < 8; ++j) acc[i][j] = 0.f;

    f32x4 wr[8];
#pragma unroll
    for (int p = 0; p < 8; ++p) {
        const int ml = row + p * 32;
        wr[p] = *(const f32x4*)(W1 + ((size_t)(n * MO_ + mo0 + ml) * CIN_ + 0 * 32 + cu8 * 4));
    }

    for (int ch = 0; ch < 4; ++ch) {
        __syncthreads();
#pragma unroll
        for (int p = 0; p < 8; ++p) {
            const int ml = row + p * 32;
            ws4[ml * 8 + (cu8 ^ (ml & 7))] = wr[p];
        }
        __syncthreads();
        if (ch < 3) {
#pragma unroll
            for (int p = 0; p < 8; ++p) {
                const int ml = row + p * 32;
                wr[p] = *(const f32x4*)(W1 + ((size_t)(n * MO_ + mo0 + ml) * CIN_ + (ch + 1) * 32 + cu8 * 4));
            }
        }
#pragma unroll
        for (int c4 = 0; c4 < 8; ++c4) {
            f32x4 wv[4];
#pragma unroll
            for (int i = 0; i < 4; ++i)
                wv[i] = ws4[(l + i * 64) * 8 + (c4 ^ (l & 7))];
            f32x4 xq[8];
#pragma unroll
            for (int j = 0; j < 8; ++j)
                xq[j] = xs4[(bg * 8 + j) * 32 + ch * 8 + c4];
#pragma unroll
            for (int i = 0; i < 4; ++i)
#pragma unroll
                for (int j = 0; j < 8; ++j) {
                    acc[i][j] += wv[i][0] * xq[j][0];
                    acc[i][j] += wv[i][1] * xq[j][1];
                    acc[i][j] += wv[i][2] * xq[j][2];
                    acc[i][j] += wv[i][3] * xq[j][3];
                }
        }
    }

#pragma unroll
    for (int i = 0; i < 4; ++i)
#pragma unroll
        for (int j = 0; j < 8; ++j)
            u[((size_t)n * NBT_ + bg * 8 + j) * MO_ + mo0 + i * 64 + l] = acc[i][j];
}

// ---------------------------------------------------------------------------
// Group barrier: 32 dispatch-adjacent blocks of one bl-group. Sense-reversing,
// device-scope atomics, agent-scope fences. Deadlock-proof: only needs 32
// blocks resident (trivially true at any occupancy); values order-independent.
// ---------------------------------------------------------------------------
static __device__ __forceinline__ void gbar(unsigned* cnt, unsigned* gen) {
    __syncthreads();
    if (threadIdx.x == 0) {
        __threadfence();                          // release our global writes
        const unsigned g = atomicAdd(gen, 0u);    // coherent-point read
        const unsigned a = atomicAdd(cnt, 1u);
        if (a == 31u) {
            atomicExch(cnt, 0u);
            __threadfence();
            atomicAdd(gen, 1u);                   // open next generation
        } else {
            while (atomicAdd(gen, 0u) == g) { __builtin_amdgcn_s_sleep(2); }
        }
        __threadfence();                          // acquire others' writes
    }
    __syncthreads();
}

// ---------------------------------------------------------------------------
// K2 persistent routing loop for one 16-b half. grid = 512 = 16 bl-groups x 32
// qq; block 256 = 4 waves. Phases per group: mean -> bar -> 9x [route -> bar
// -> squash -> bar]. Route/n-loop/LDS-combine are R10-verbatim (bit-exact);
// mean uses a fixed 2-way n-split; squash sums 32 partials in R10's q-order.
// ---------------------------------------------------------------------------
__global__ __launch_bounds__(256, 2) void k_routeloop(const float* __restrict__ u,
                                                      float* __restrict__ vws,
                                                      float* __restrict__ blog,
                                                      float* __restrict__ spart,
                                                      float* __restrict__ out,
                                                      unsigned* __restrict__ ctrl,
                                                      int bofs) {
    const int bid = blockIdx.x;
    const int bl  = bid >> 5;            // group = 32 consecutive blocks
    const int qq  = bid & 31;
    const int t   = threadIdx.x;
    const int w   = t >> 6;
    const int l   = t & 63;
    const int sub = l >> 3;

    unsigned* cnt = ctrl + bl * 64;      // 256 B per group (padded line)
    unsigned* gen = cnt + 1;

    __shared__ f32x4 lred[4][16][64];    // 64 KB combine stage

    // ---- phase 0: iteration-1 v (uniform c = 1/128). Block does 128 mo's,
    // 2 threads per mo (fixed n-halves), combine via shfl_xor(1). ----
    {
        const int mo   = qq * 128 + (t >> 1);
        const int half = t & 1;
        const float* up = u + (size_t)(bofs + bl) * MO_ + mo;
        float p = 0.f;
#pragma unroll 8
        for (int n = half * 256; n < half * 256 + 256; ++n)
            p += up[(size_t)n * NBT_ * MO_];
        const float pp = p + __shfl_xor(p, 1, 64);
        if (half == 0) {
            const float s = pp * (1.0f / 128.0f);
            const float s2 = s * s;
            vws[bl * MO_ + mo] = (sqrtf(s2) / (0.5f + s2)) * s;
        }
    }
    gbar(cnt, gen);

    for (int it = 1; it <= 9; ++it) {
        // ---- route phase (R10 body verbatim; it==1 is the blog=0 case) ----
        f32x4 vr[16];
#pragma unroll
        for (int j = 0; j < 16; ++j)
            vr[j] = *(const f32x4*)(vws + (size_t)bl * MO_ + (j * 64 + l) * 4);

        f32x4 sacc[16];
#pragma unroll
        for (int j = 0; j < 16; ++j) sacc[j] = (f32x4){0.f, 0.f, 0.f, 0.f};

        for (int nn = 0; nn < 4; ++nn) {
            const int n = qq * 16 + w * 4 + nn;
            const f32x4* up = (const f32x4*)(u + ((size_t)n * NBT_ + bofs + bl) * MO_);
            f32x4 ur[16];
#pragma unroll
            for (int j = 0; j < 16; ++j) ur[j] = up[j * 64 + l];

            float* bp = blog + ((size_t)bl * NIN_ + n) * NOUT_;
            float bn[16];
            float mx = -1e30f;
#pragma unroll
            for (int j = 0; j < 16; ++j) {
                float p = vr[j][0] * ur[j][0] + vr[j][1] * ur[j][1]
                        + vr[j][2] * ur[j][2] + vr[j][3] * ur[j][3];
                p += __shfl_xor(p, 1, 64);
                p += __shfl_xor(p, 2, 64);
                p += __shfl_xor(p, 4, 64);
                const float old = (it == 1) ? 0.f : bp[j * 8 + sub];
                bn[j] = old + p;
                mx = fmaxf(mx, bn[j]);
            }
            if ((l & 7) == 0) {
#pragma unroll
                for (int j = 0; j < 16; ++j) bp[j * 8 + sub] = bn[j];
            }
            mx = fmaxf(mx, __shfl_xor(mx, 8, 64));
            mx = fmaxf(mx, __shfl_xor(mx, 16, 64));
            mx = fmaxf(mx, __shfl_xor(mx, 32, 64));
            float se = 0.f;
#pragma unroll
            for (int j = 0; j < 16; ++j) {
                bn[j] = expf(bn[j] - mx);
                se += bn[j];
            }
            se += __shfl_xor(se, 8, 64);
            se += __shfl_xor(se, 16, 64);
            se += __shfl_xor(se, 32, 64);
            const float inv = 1.0f / se;
#pragma unroll
            for (int j = 0; j < 16; ++j) {
                const float c = bn[j] * inv;
                sacc[j][0] += c * ur[j][0]; sacc[j][1] += c * ur[j][1];
                sacc[j][2] += c * ur[j][2]; sacc[j][3] += c * ur[j][3];
            }
        }

        // in-block combine: all waves store, one barrier, wave w sums 4w..4w+3
#pragma unroll
        for (int j = 0; j < 16; ++j) lred[w][j][l] = sacc[j];
        __syncthreads();

        f32x4* sp = (f32x4*)(spart + ((size_t)qq * RB_ + bl) * MO_);
#pragma unroll
        for (int jj = 0; jj < 4; ++jj) {
            const int j = w * 4 + jj;
            const f32x4 a0 = lred[0][j][l];
            const f32x4 a1 = lred[1][j][l];
            const f32x4 a2 = lred[2][j][l];
            const f32x4 a3 = lred[3][j][l];
            f32x4 r;
#pragma unroll
            for (int c = 0; c < 4; ++c) r[c] = ((a0[c] + a1[c]) + a2[c]) + a3[c];
            sp[j * 64 + l] = r;
        }
        gbar(cnt, gen);

        // ---- squash phase: thread t<32 owns f32x4 unit qq*32+t of bl's row,
        // summing the 32 q-partials in R10's sequential order (bit-exact). ----
        if (t < 32) {
            const int uidx = qq * 32 + t;            // 0..1023
            const f32x4* sp4 = (const f32x4*)spart;
            const size_t stride4 = (size_t)RB_ * MO_ / 4;
            const size_t base4   = ((size_t)bl * MO_) / 4 + uidx;
            f32x4 s = {0.f, 0.f, 0.f, 0.f};
#pragma unroll 8
            for (int q = 0; q < NQ2_; ++q) {
                const f32x4 vq = sp4[q * stride4 + base4];
                s[0] += vq[0]; s[1] += vq[1]; s[2] += vq[2]; s[3] += vq[3];
            }
            f32x4 v;
#pragma unroll
            for (int c = 0; c < 4; ++c) {
                const float s2 = s[c] * s[c];
                v[c] = (sqrtf(s2) / (0.5f + s2)) * s[c];
            }
            if (it < 9) {
                ((f32x4*)vws)[((size_t)bl * MO_) / 4 + uidx] = v;
            } else {
                ((f32x4*)out)[((size_t)(bofs + bl) * MO_) / 4 + uidx] = v;
                float v2 = v[0] * v[0] + v[1] * v[1] + v[2] * v[2] + v[3] * v[3];
                v2 += __shfl_xor(v2, 1, 64);
                v2 += __shfl_xor(v2, 2, 64);
                v2 += __shfl_xor(v2, 4, 64);
                if ((t & 7) == 0) {
                    const int m = uidx >> 3;
                    out[131072 + (size_t)(bofs + bl) * NOUT_ + m] = sqrtf(v2);
                }
            }
        }
        if (it < 9) gbar(cnt, gen);   // next route reads vws
    }
}

// ---------------------------------------------------------------------------
extern "C" void kernel_launch(void* const* d_in, const int* in_sizes, int n_in,
                              void* d_out, int out_size, void* d_ws, size_t ws_size,
                              hipStream_t stream) {
    const float* x  = (const float*)d_in[0];
    const float* W1 = (const float*)d_in[1];
    float* out = (float*)d_out;

    char* ws = (char*)d_ws;
    const size_t bytes_u  = (size_t)NBT_ * NIN_ * MO_ * 4;        // 268 MB
    const size_t bytes_bl = (size_t)RB_ * NIN_ * NOUT_ * 4;       // 4.2 MB
    const size_t bytes_v  = (size_t)RB_ * MO_ * 4;                // 0.26 MB
    const size_t bytes_sp = (size_t)NQ2_ * RB_ * MO_ * 4;         // 8.4 MB
    const size_t bytes_ct = 16 * 64 * sizeof(unsigned);           // 4 KB
    const size_t need = bytes_u + bytes_bl + bytes_v + bytes_sp + bytes_ct;
    if (ws_size < need) return;   // ws observed ≈ 4.3 GB; ample

    float*    u     = (float*)(ws);
    float*    blog  = (float*)(ws + bytes_u);
    float*    vws   = (float*)(ws + bytes_u + bytes_bl);
    float*    spart = (float*)(ws + bytes_u + bytes_bl + bytes_v);
    unsigned* ctrl  = (unsigned*)(ws + bytes_u + bytes_bl + bytes_v + bytes_sp);

    // zero barrier state once per call (first run: clears 0xAA poison;
    // barriers themselves leave cnt=0 and gen monotone, handled by design)
    hipMemsetAsync(ctrl, 0, bytes_ct, stream);

    // build all 32 b at once: W read exactly once
    k_build<<<8192, 256, 0, stream>>>(x, W1, u);

    // one persistent kernel per 16-b half (u-half stays L3-affine)
    k_routeloop<<<RB_ * NQ2_, 256, 0, stream>>>(u, vws, blog, spart, out, ctrl, 0);
    k_routeloop<<<RB_ * NQ2_, 256, 0, stream>>>(u, vws, blog, spart, out, ctrl, RB_);
}

// Round 13
// 1167.531 us; speedup vs baseline: 1.7531x; 1.7531x over previous
//
#include <hip/hip_runtime.h>
#include <hip/hip_bf16.h>
#include <stdint.h>
#include <math.h>

#define NIN_  512
#define NOUT_ 128
#define CIN_  128
#define COUT_ 32
#define MO_   4096   // NOUT*COUT
#define NBT_  32     // build batch (all of B)
#define RB_   8      // routed b-quarter width
#define NQ2_  64     // route n-chunks per quarter (8 n each; 2 n per wave)

typedef __attribute__((ext_vector_type(4))) float f32x4;

// ---------------------------------------------------------------------------
// K1 (fp32): u[n][bl(32)][mo] = sum_c W1[n][mo][c] * x[bl][n][c]
// grid = 8192 = 512 n * 16 mo-tiles(256); block 256 = 4 waves.
// (R10-verbatim — near BW-bound; R9 showed any fusion into it regresses)
// ---------------------------------------------------------------------------
__global__ __launch_bounds__(256) void k_build(const float* __restrict__ x,
                                               const float* __restrict__ W1,
                                               float* __restrict__ u) {
    const int n   = blockIdx.x >> 4;
    const int mt  = blockIdx.x & 15;
    const int mo0 = mt * 256;
    const int t   = threadIdx.x;
    const int l   = t & 63;
    const int bg  = t >> 6;

    __shared__ f32x4 xs4[32 * 32];   // [bl][cu]  16 KB
    __shared__ f32x4 ws4[256 * 8];   // swizzled   32 KB

    for (int k = t; k < NBT_ * 32; k += 256) {
        const int bl = k >> 5;
        const int cu = k & 31;
        xs4[k] = *(const f32x4*)(x + (((size_t)bl * NIN_ + n) * CIN_ + cu * 4));
    }

    const int cu8 = t & 7;
    const int row = t >> 3;

    float acc[4][8];
#pragma unroll
    for (int i = 0; i < 4; ++i)
#pragma unroll
        for (int j = 0; j < 8; ++j) acc[i][j] = 0.f;

    f32x4 wr[8];
#pragma unroll
    for (int p = 0; p < 8; ++p) {
        const int ml = row + p * 32;
        wr[p] = *(const f32x4*)(W1 + ((size_t)(n * MO_ + mo0 + ml) * CIN_ + 0 * 32 + cu8 * 4));
    }

    for (int ch = 0; ch < 4; ++ch) {
        __syncthreads();
#pragma unroll
        for (int p = 0; p < 8; ++p) {
            const int ml = row + p * 32;
            ws4[ml * 8 + (cu8 ^ (ml & 7))] = wr[p];
        }
        __syncthreads();
        if (ch < 3) {
#pragma unroll
            for (int p = 0; p < 8; ++p) {
                const int ml = row + p * 32;
                wr[p] = *(const f32x4*)(W1 + ((size_t)(n * MO_ + mo0 + ml) * CIN_ + (ch + 1) * 32 + cu8 * 4));
            }
        }
#pragma unroll
        for (int c4 = 0; c4 < 8; ++c4) {
            f32x4 wv[4];
#pragma unroll
            for (int i = 0; i < 4; ++i)
                wv[i] = ws4[(l + i * 64) * 8 + (c4 ^ (l & 7))];
            f32x4 xq[8];
#pragma unroll
            for (int j = 0; j < 8; ++j)
                xq[j] = xs4[(bg * 8 + j) * 32 + ch * 8 + c4];
#pragma unroll
            for (int i = 0; i < 4; ++i)
#pragma unroll
                for (int j = 0; j < 8; ++j) {
                    acc[i][j] += wv[i][0] * xq[j][0];
                    acc[i][j] += wv[i][1] * xq[j][1];
                    acc[i][j] += wv[i][2] * xq[j][2];
                    acc[i][j] += wv[i][3] * xq[j][3];
                }
        }
    }

#pragma unroll
    for (int i = 0; i < 4; ++i)
#pragma unroll
        for (int j = 0; j < 8; ++j)
            u[((size_t)n * NBT_ + bg * 8 + j) * MO_ + mo0 + i * 64 + l] = acc[i][j];
}

// ---------------------------------------------------------------------------
// K_mean: iteration-1 v directly from u (c uniform = 1/128 exactly):
// s[bl][mo] = (1/128)*sum_n u[n][bofs+bl][mo]; v = squash(s) -> vws.
// grid = RB_*MO_/256 = 128; deterministic fixed-order n loop; also warms L3
// with this quarter's u right before its routing iterations.
// ---------------------------------------------------------------------------
__global__ __launch_bounds__(256) void k_mean(const float* __restrict__ u,
                                              float* __restrict__ vws, int bofs) {
    const int j  = blockIdx.x * 256 + threadIdx.x;   // bl*MO_ + mo (quarter-local)
    const int bl = j >> 12;
    const int mo = j & (MO_ - 1);
    const float* up = u + (size_t)(bofs + bl) * MO_ + mo;
    float s = 0.f;
#pragma unroll 8
    for (int n = 0; n < NIN_; ++n) s += up[(size_t)n * NBT_ * MO_];
    s *= (1.0f / 128.0f);
    const float s2 = s * s;
    vws[j] = (sqrtf(s2) / (0.5f + s2)) * s;
}

// ---------------------------------------------------------------------------
// K2 fused routing iteration (fp32) — R10 inner body verbatim, quarter form.
// MODE: 1 = first agree (blog=0), 2 = normal
// grid = RB_*NQ2_ = 512; block 256 = 4 waves, ALL on the same bl; wave w takes
// n's {qq*8+w*2, qq*8+w*2+1}. End: one-barrier LDS combine of the 4 waves'
// sacc (fixed order w0+w1+w2+w3) -> spart gets NQ2_=64 partials.
// Unit layout: f32x4 unit f = j*64+l; m = j*8 + (l>>3); o-quad = l&7.
// n-loop is wave-private (shfl-only softmax) — post-timing-safe.
// ---------------------------------------------------------------------------
template<int MODE>
__global__ __launch_bounds__(256) void k_route(const float* __restrict__ u,
                                               const float* __restrict__ vws,
                                               float* __restrict__ blog,
                                               float* __restrict__ spart,
                                               int bofs) {
    const int bl  = blockIdx.x & 7;      // local b 0..7
    const int qq  = blockIdx.x >> 3;     // 0..NQ2_-1
    const int w   = threadIdx.x >> 6;
    const int l   = threadIdx.x & 63;
    const int sub = l >> 3;

    __shared__ f32x4 lred[4][16][64];    // 64 KB combine stage

    f32x4 vr[16];
#pragma unroll
    for (int j = 0; j < 16; ++j)
        vr[j] = *(const f32x4*)(vws + (size_t)bl * MO_ + (j * 64 + l) * 4);

    f32x4 sacc[16];
#pragma unroll
    for (int j = 0; j < 16; ++j) sacc[j] = (f32x4){0.f, 0.f, 0.f, 0.f};

    for (int nn = 0; nn < 2; ++nn) {
        const int n = qq * 8 + w * 2 + nn;
        const f32x4* up = (const f32x4*)(u + ((size_t)n * NBT_ + bofs + bl) * MO_);
        f32x4 ur[16];
#pragma unroll
        for (int j = 0; j < 16; ++j) ur[j] = up[j * 64 + l];

        float* bp = blog + ((size_t)bl * NIN_ + n) * NOUT_;
        float bn[16];
        float mx = -1e30f;
#pragma unroll
        for (int j = 0; j < 16; ++j) {
            float p = vr[j][0] * ur[j][0] + vr[j][1] * ur[j][1]
                    + vr[j][2] * ur[j][2] + vr[j][3] * ur[j][3];
            p += __shfl_xor(p, 1, 64);
            p += __shfl_xor(p, 2, 64);
            p += __shfl_xor(p, 4, 64);
            const float old = (MODE == 1) ? 0.f : bp[j * 8 + sub];
            bn[j] = old + p;
            mx = fmaxf(mx, bn[j]);
        }
        if ((l & 7) == 0) {
#pragma unroll
            for (int j = 0; j < 16; ++j) bp[j * 8 + sub] = bn[j];
        }
        mx = fmaxf(mx, __shfl_xor(mx, 8, 64));
        mx = fmaxf(mx, __shfl_xor(mx, 16, 64));
        mx = fmaxf(mx, __shfl_xor(mx, 32, 64));
        float se = 0.f;
#pragma unroll
        for (int j = 0; j < 16; ++j) {
            bn[j] = expf(bn[j] - mx);
            se += bn[j];
        }
        se += __shfl_xor(se, 8, 64);
        se += __shfl_xor(se, 16, 64);
        se += __shfl_xor(se, 32, 64);
        const float inv = 1.0f / se;
#pragma unroll
        for (int j = 0; j < 16; ++j) {
            const float c = bn[j] * inv;
            sacc[j][0] += c * ur[j][0]; sacc[j][1] += c * ur[j][1];
            sacc[j][2] += c * ur[j][2]; sacc[j][3] += c * ur[j][3];
        }
    }

    // in-block combine: all waves store, one barrier, wave w sums units 4w..4w+3
#pragma unroll
    for (int j = 0; j < 16; ++j) lred[w][j][l] = sacc[j];
    __syncthreads();

    f32x4* sp = (f32x4*)(spart + ((size_t)qq * RB_ + bl) * MO_);
#pragma unroll
    for (int jj = 0; jj < 4; ++jj) {
        const int j = w * 4 + jj;
        const f32x4 a0 = lred[0][j][l];
        const f32x4 a1 = lred[1][j][l];
        const f32x4 a2 = lred[2][j][l];
        const f32x4 a3 = lred[3][j][l];
        f32x4 r;
#pragma unroll
        for (int c = 0; c < 4; ++c) r[c] = ((a0[c] + a1[c]) + a2[c]) + a3[c];
        sp[j * 64 + l] = r;
    }
}

// ---------------------------------------------------------------------------
// K3: s = sum_q spart (NQ2_ partials); v = squash(s) -> vws
// ---------------------------------------------------------------------------
__global__ __launch_bounds__(256) void k_squash_mid(const float* __restrict__ spart,
                                                    float* __restrict__ vws) {
    const int j = blockIdx.x * 256 + threadIdx.x;   // bl*MO_ + mo (quarter-local)
    const size_t stride = (size_t)RB_ * MO_;
    float s = 0.f;
#pragma unroll 8
    for (int q = 0; q < NQ2_; ++q) s += spart[q * stride + j];
    const float s2 = s * s;
    vws[j] = (sqrtf(s2) / (0.5f + s2)) * s;
}

// ---------------------------------------------------------------------------
// K4: final squash -> poses (fp32, [b][m][o]) + activations [b][m]
// ---------------------------------------------------------------------------
__global__ __launch_bounds__(256) void k_squash_fin(const float* __restrict__ spart,
                                                    float* __restrict__ out,
                                                    int b0) {
    const int j = blockIdx.x * 256 + threadIdx.x;   // bl*MO_ + mo (quarter-local)
    const size_t stride = (size_t)RB_ * MO_;
    float s = 0.f;
#pragma unroll 8
    for (int q = 0; q < NQ2_; ++q) s += spart[q * stride + j];
    const float s2 = s * s;
    const float v = (sqrtf(s2) / (0.5f + s2)) * s;
    out[(size_t)b0 * MO_ + j] = v;

    float v2 = v * v;
#pragma unroll
    for (int d = 16; d >= 1; d >>= 1) v2 += __shfl_xor(v2, d, 64);
    if ((j & 31) == 0) {
        const int bl = j >> 12;
        const int m  = (j >> 5) & 127;
        out[131072 + (size_t)(b0 + bl) * NOUT_ + m] = sqrtf(v2);
    }
}

// ---------------------------------------------------------------------------
extern "C" void kernel_launch(void* const* d_in, const int* in_sizes, int n_in,
                              void* d_out, int out_size, void* d_ws, size_t ws_size,
                              hipStream_t stream) {
    const float* x  = (const float*)d_in[0];
    const float* W1 = (const float*)d_in[1];
    float* out = (float*)d_out;

    char* ws = (char*)d_ws;
    const size_t bytes_u  = (size_t)NBT_ * NIN_ * MO_ * 4;        // 268 MB
    const size_t bytes_bl = (size_t)RB_ * NIN_ * NOUT_ * 4;       // 2.1 MB
    const size_t bytes_v  = (size_t)RB_ * MO_ * 4;                // 131 KB
    const size_t bytes_sp = (size_t)NQ2_ * RB_ * MO_ * 4;         // 8.4 MB
    const size_t need = bytes_u + bytes_bl + bytes_v + bytes_sp;
    if (ws_size < need) return;   // ws observed ≈ 4.3 GB; ample

    float* u     = (float*)(ws);
    float* blog  = (float*)(ws + bytes_u);
    float* vws   = (float*)(ws + bytes_u + bytes_bl);
    float* spart = (float*)(ws + bytes_u + bytes_bl + bytes_v);

    // build all 32 b at once: W read exactly once
    k_build<<<8192, 256, 0, stream>>>(x, W1, u);

    const int rgrid = RB_ * NQ2_;         // 512
    const int sgrid = (RB_ * MO_) / 256;  // 128

    // route each 8-b quarter fully while its 67 MB u-quarter stays L3-resident
    for (int h = 0; h < 4; ++h) {
        const int bofs = h * RB_;

        // iteration 1: v from direct mean (uniform c) — also warms L3 with u-quarter
        k_mean<<<sgrid, 256, 0, stream>>>(u, vws, bofs);

        for (int it = 1; it <= 9; ++it) {
            if (it == 1) k_route<1><<<rgrid, 256, 0, stream>>>(u, vws, blog, spart, bofs);
            else         k_route<2><<<rgrid, 256, 0, stream>>>(u, vws, blog, spart, bofs);
            if (it < 9) k_squash_mid<<<sgrid, 256, 0, stream>>>(spart, vws);
            else        k_squash_fin<<<sgrid, 256, 0, stream>>>(spart, out, bofs);
        }
    }
}

// Round 14
// 927.763 us; speedup vs baseline: 2.2062x; 1.2584x over previous
//
#include <hip/hip_runtime.h>
#include <hip/hip_bf16.h>
#include <stdint.h>
#include <math.h>

#define NIN_  512
#define NOUT_ 128
#define CIN_  128
#define COUT_ 32
#define MO_   4096   // NOUT*COUT
#define NBT_  32     // build batch (all of B)
#define RB_   16     // routed b-half width
#define NQ2_  32     // route n-chunks per half (16 n each; 4 n per wave)

typedef __attribute__((ext_vector_type(4))) float f32x4;

// ---------------------------------------------------------------------------
// K1 (fp32): u[n][bl(32)][mo] = sum_c W1[n][mo][c] * x[bl][n][c]
// grid = 8192 = 512 n * 16 mo-tiles(256); block 256 = 4 waves.
// W staged in LDS as XOR-swizzled float4 units (conflict-free b128).
// (R8/R10-verbatim — proven near BW-bound)
// ---------------------------------------------------------------------------
__global__ __launch_bounds__(256) void k_build(const float* __restrict__ x,
                                               const float* __restrict__ W1,
                                               float* __restrict__ u) {
    const int n   = blockIdx.x >> 4;
    const int mt  = blockIdx.x & 15;
    const int mo0 = mt * 256;
    const int t   = threadIdx.x;
    const int l   = t & 63;
    const int bg  = t >> 6;

    __shared__ f32x4 xs4[32 * 32];   // [bl][cu]  16 KB
    __shared__ f32x4 ws4[256 * 8];   // swizzled   32 KB

    for (int k = t; k < NBT_ * 32; k += 256) {
        const int bl = k >> 5;
        const int cu = k & 31;
        xs4[k] = *(const f32x4*)(x + (((size_t)bl * NIN_ + n) * CIN_ + cu * 4));
    }

    const int cu8 = t & 7;
    const int row = t >> 3;

    float acc[4][8];
#pragma unroll
    for (int i = 0; i < 4; ++i)
#pragma unroll
        for (int j = 0; j < 8; ++j) acc[i][j] = 0.f;

    f32x4 wr[8];
#pragma unroll
    for (int p = 0; p < 8; ++p) {
        const int ml = row + p * 32;
        wr[p] = *(const f32x4*)(W1 + ((size_t)(n * MO_ + mo0 + ml) * CIN_ + 0 * 32 + cu8 * 4));
    }

    for (int ch = 0; ch < 4; ++ch) {
        __syncthreads();
#pragma unroll
        for (int p = 0; p < 8; ++p) {
            const int ml = row + p * 32;
            ws4[ml * 8 + (cu8 ^ (ml & 7))] = wr[p];
        }
        __syncthreads();
        if (ch < 3) {
#pragma unroll
            for (int p = 0; p < 8; ++p) {
                const int ml = row + p * 32;
                wr[p] = *(const f32x4*)(W1 + ((size_t)(n * MO_ + mo0 + ml) * CIN_ + (ch + 1) * 32 + cu8 * 4));
            }
        }
#pragma unroll
        for (int c4 = 0; c4 < 8; ++c4) {
            f32x4 wv[4];
#pragma unroll
            for (int i = 0; i < 4; ++i)
                wv[i] = ws4[(l + i * 64) * 8 + (c4 ^ (l & 7))];
            f32x4 xq[8];
#pragma unroll
            for (int j = 0; j < 8; ++j)
                xq[j] = xs4[(bg * 8 + j) * 32 + ch * 8 + c4];
#pragma unroll
            for (int i = 0; i < 4; ++i)
#pragma unroll
                for (int j = 0; j < 8; ++j) {
                    acc[i][j] += wv[i][0] * xq[j][0];
                    acc[i][j] += wv[i][1] * xq[j][1];
                    acc[i][j] += wv[i][2] * xq[j][2];
                    acc[i][j] += wv[i][3] * xq[j][3];
                }
        }
    }

#pragma unroll
    for (int i = 0; i < 4; ++i)
#pragma unroll
        for (int j = 0; j < 8; ++j)
            u[((size_t)n * NBT_ + bg * 8 + j) * MO_ + mo0 + i * 64 + l] = acc[i][j];
}

// ---------------------------------------------------------------------------
// K_mean: iteration-1 v directly from u (c uniform = 1/128 exactly):
// s[bl][mo] = (1/128)*sum_n u[n][bofs+bl][mo]; v = |s|*s/(0.5+s^2) -> vws.
// grid = RB_*MO_/256 = 256; deterministic fixed-order n loop; also warms L3
// with this half's u right before its routing iterations.
// ---------------------------------------------------------------------------
__global__ __launch_bounds__(256) void k_mean(const float* __restrict__ u,
                                              float* __restrict__ vws, int bofs) {
    const int j  = blockIdx.x * 256 + threadIdx.x;   // bl*MO_ + mo (half-local)
    const int bl = j >> 12;
    const int mo = j & (MO_ - 1);
    const float* up = u + (size_t)(bofs + bl) * MO_ + mo;
    float s = 0.f;
#pragma unroll 8
    for (int n = 0; n < NIN_; ++n) s += up[(size_t)n * NBT_ * MO_];
    s *= (1.0f / 128.0f);
    const float s2 = s * s;
    vws[j] = (sqrtf(s2) / (0.5f + s2)) * s;
}

// ---------------------------------------------------------------------------
// K2 fused routing iteration (fp32) — R4/R8 inner body verbatim.
// MODE: 1 = first agree (blog=0), 2 = normal
// grid = RB_*NQ2_ = 512; block 256 = 4 waves, ALL on the same bl; wave w takes
// n-chunk qq*4+w (4 n each). End: one-barrier LDS combine of the 4 waves'
// sacc (fixed order w0+w1+w2+w3) -> spart gets 32 partials instead of 128.
// Unit layout: f32x4 unit f = j*64+l; m = j*8 + (l>>3); o-quad = l&7.
// n-loop is wave-private (shfl-only softmax) — post-timing-safe.
// ---------------------------------------------------------------------------
template<int MODE>
__global__ __launch_bounds__(256) void k_route(const float* __restrict__ u,
                                               const float* __restrict__ vws,
                                               float* __restrict__ blog,
                                               float* __restrict__ spart,
                                               int bofs) {
    const int bl  = blockIdx.x & 15;     // local b 0..15
    const int qq  = blockIdx.x >> 4;     // 0..NQ2_-1
    const int w   = threadIdx.x >> 6;
    const int l   = threadIdx.x & 63;
    const int sub = l >> 3;

    __shared__ f32x4 lred[4][16][64];    // 64 KB combine stage

    f32x4 vr[16];
#pragma unroll
    for (int j = 0; j < 16; ++j)
        vr[j] = *(const f32x4*)(vws + (size_t)bl * MO_ + (j * 64 + l) * 4);

    f32x4 sacc[16];
#pragma unroll
    for (int j = 0; j < 16; ++j) sacc[j] = (f32x4){0.f, 0.f, 0.f, 0.f};

    for (int nn = 0; nn < 4; ++nn) {
        const int n = qq * 16 + w * 4 + nn;
        const f32x4* up = (const f32x4*)(u + ((size_t)n * NBT_ + bofs + bl) * MO_);
        f32x4 ur[16];
#pragma unroll
        for (int j = 0; j < 16; ++j) ur[j] = up[j * 64 + l];

        float* bp = blog + ((size_t)bl * NIN_ + n) * NOUT_;
        float bn[16];
        float mx = -1e30f;
#pragma unroll
        for (int j = 0; j < 16; ++j) {
            float p = vr[j][0] * ur[j][0] + vr[j][1] * ur[j][1]
                    + vr[j][2] * ur[j][2] + vr[j][3] * ur[j][3];
            p += __shfl_xor(p, 1, 64);
            p += __shfl_xor(p, 2, 64);
            p += __shfl_xor(p, 4, 64);
            const float old = (MODE == 1) ? 0.f : bp[j * 8 + sub];
            bn[j] = old + p;
            mx = fmaxf(mx, bn[j]);
        }
        if ((l & 7) == 0) {
#pragma unroll
            for (int j = 0; j < 16; ++j) bp[j * 8 + sub] = bn[j];
        }
        mx = fmaxf(mx, __shfl_xor(mx, 8, 64));
        mx = fmaxf(mx, __shfl_xor(mx, 16, 64));
        mx = fmaxf(mx, __shfl_xor(mx, 32, 64));
        float se = 0.f;
#pragma unroll
        for (int j = 0; j < 16; ++j) {
            bn[j] = expf(bn[j] - mx);
            se += bn[j];
        }
        se += __shfl_xor(se, 8, 64);
        se += __shfl_xor(se, 16, 64);
        se += __shfl_xor(se, 32, 64);
        const float inv = 1.0f / se;
#pragma unroll
        for (int j = 0; j < 16; ++j) {
            const float c = bn[j] * inv;
            sacc[j][0] += c * ur[j][0]; sacc[j][1] += c * ur[j][1];
            sacc[j][2] += c * ur[j][2]; sacc[j][3] += c * ur[j][3];
        }
    }

    // in-block combine: all waves store, one barrier, wave w sums units 4w..4w+3
#pragma unroll
    for (int j = 0; j < 16; ++j) lred[w][j][l] = sacc[j];
    __syncthreads();

    f32x4* sp = (f32x4*)(spart + ((size_t)qq * RB_ + bl) * MO_);
#pragma unroll
    for (int jj = 0; jj < 4; ++jj) {
        const int j = w * 4 + jj;
        const f32x4 a0 = lred[0][j][l];
        const f32x4 a1 = lred[1][j][l];
        const f32x4 a2 = lred[2][j][l];
        const f32x4 a3 = lred[3][j][l];
        f32x4 r;
#pragma unroll
        for (int c = 0; c < 4; ++c) r[c] = ((a0[c] + a1[c]) + a2[c]) + a3[c];
        sp[j * 64 + l] = r;
    }
}

// ---------------------------------------------------------------------------
// K3: s = sum_q spart (NQ2_ partials); v = |s|*s/(0.5+s^2) -> vws
// ---------------------------------------------------------------------------
__global__ __launch_bounds__(256) void k_squash_mid(const float* __restrict__ spart,
                                                    float* __restrict__ vws) {
    const int j = blockIdx.x * 256 + threadIdx.x;   // bl*MO_ + mo (half-local)
    const size_t stride = (size_t)RB_ * MO_;
    float s = 0.f;
#pragma unroll 8
    for (int q = 0; q < NQ2_; ++q) s += spart[q * stride + j];
    const float s2 = s * s;
    vws[j] = (sqrtf(s2) / (0.5f + s2)) * s;
}

// ---------------------------------------------------------------------------
// K4: final squash -> poses (fp32, [b][m][o]) + activations [b][m]
// ---------------------------------------------------------------------------
__global__ __launch_bounds__(256) void k_squash_fin(const float* __restrict__ spart,
                                                    float* __restrict__ out,
                                                    int b0) {
    const int j = blockIdx.x * 256 + threadIdx.x;   // bl*MO_ + mo (half-local)
    const size_t stride = (size_t)RB_ * MO_;
    float s = 0.f;
#pragma unroll 8
    for (int q = 0; q < NQ2_; ++q) s += spart[q * stride + j];
    const float s2 = s * s;
    const float v = (sqrtf(s2) / (0.5f + s2)) * s;
    out[(size_t)b0 * MO_ + j] = v;

    float v2 = v * v;
#pragma unroll
    for (int d = 16; d >= 1; d >>= 1) v2 += __shfl_xor(v2, d, 64);
    if ((j & 31) == 0) {
        const int bl = j >> 12;
        const int m  = (j >> 5) & 127;
        out[131072 + (size_t)(b0 + bl) * NOUT_ + m] = sqrtf(v2);
    }
}

// ---------------------------------------------------------------------------
extern "C" void kernel_launch(void* const* d_in, const int* in_sizes, int n_in,
                              void* d_out, int out_size, void* d_ws, size_t ws_size,
                              hipStream_t stream) {
    const float* x  = (const float*)d_in[0];
    const float* W1 = (const float*)d_in[1];
    float* out = (float*)d_out;

    char* ws = (char*)d_ws;
    const size_t bytes_u  = (size_t)NBT_ * NIN_ * MO_ * 4;        // 268 MB
    const size_t bytes_bl = (size_t)RB_ * NIN_ * NOUT_ * 4;       // 4.2 MB
    const size_t bytes_v  = (size_t)RB_ * MO_ * 4;                // 0.26 MB
    const size_t bytes_sp = (size_t)NQ2_ * RB_ * MO_ * 4;         // 8.4 MB
    const size_t need = bytes_u + bytes_bl + bytes_v + bytes_sp;
    if (ws_size < need) return;   // ws observed ≈ 4.3 GB; ample

    float* u     = (float*)(ws);
    float* blog  = (float*)(ws + bytes_u);
    float* vws   = (float*)(ws + bytes_u + bytes_bl);
    float* spart = (float*)(ws + bytes_u + bytes_bl + bytes_v);

    // build all 32 b at once: W read exactly once
    k_build<<<8192, 256, 0, stream>>>(x, W1, u);

    const int rgrid = RB_ * NQ2_;         // 512
    const int sgrid = (RB_ * MO_) / 256;  // 256

    // route each 16-b half fully while its 134 MB u-half stays L3-affine
    for (int h = 0; h < 2; ++h) {
        const int bofs = h * RB_;

        // iteration 1: v from direct mean (uniform c) — also warms L3 with u-half
        k_mean<<<sgrid, 256, 0, stream>>>(u, vws, bofs);

        for (int it = 1; it <= 9; ++it) {
            if (it == 1) k_route<1><<<rgrid, 256, 0, stream>>>(u, vws, blog, spart, bofs);
            else         k_route<2><<<rgrid, 256, 0, stream>>>(u, vws, blog, spart, bofs);
            if (it < 9) k_squash_mid<<<sgrid, 256, 0, stream>>>(spart, vws);
            else        k_squash_fin<<<sgrid, 256, 0, stream>>>(spart, out, bofs);
        }
    }
}